// Round 2
// baseline (91.939 us; speedup 1.0000x reference)
//
#include <hip/hip_runtime.h>
#include <hip/hip_cooperative_groups.h>
#include <math.h>

namespace cg = cooperative_groups;

#define DD 256
#define DEPTH 4
#define NBLK 16
#define NTHR 256

// cls-position-only network (round-1 derivation, absmax 0.0), now parallelized:
// wide matvecs column-split across 16 blocks; narrow path redundant per block;
// 2 grid syncs per layer. Activations in d_ws (rewritten every call).
__global__ __launch_bounds__(NTHR, 1)
void netmamba_coop(const float* __restrict__ cls_token,
                   const float* __restrict__ pos_embed,
                   const float* __restrict__ norm_w,
                   const float* __restrict__ in_proj_w,
                   const float* __restrict__ conv_w,
                   const float* __restrict__ conv_b,
                   const float* __restrict__ x_proj_w,
                   const float* __restrict__ dt_proj_w,
                   const float* __restrict__ dt_proj_b,
                   const float* __restrict__ D_skip,
                   const float* __restrict__ out_proj_w,
                   const float* __restrict__ norm_f_w,
                   float* __restrict__ out,
                   float* __restrict__ ws)
{
    cg::grid_group grid = cg::this_grid();
    const int tid = threadIdx.x;
    const int bid = blockIdx.x;

    float* xc_g  = ws;            // [256] silu(conv(x-half))
    float* zv_g  = ws + DD;       // [256] z-half
    float* hv_g  = ws + 2*DD;     // [256] mixer output
    float* res_e = ws + 3*DD;     // res after even layers (0,2)
    float* res_o = ws + 4*DD;     // res after odd layers (1)

    __shared__ float hn[DD], xcl[DD], zvl[DD], yvl[DD];
    __shared__ float xdbl[48];
    __shared__ float4 part[32][8];    // in_proj partials
    __shared__ float4 part2[64][4];   // out_proj partials
    __shared__ float  xp[48][4];
    __shared__ float  red[4];
    __shared__ float  rstd_s;

    for (int L = 0; L < DEPTH; ++L) {
        // ---- Stage A: residual + rmsnorm (redundant per block) ----
        float rn;
        if (L == 0) {
            rn = cls_token[tid] + pos_embed[50*DD + tid];
        } else {
            const float* rprev = ((L-1)&1) ? res_o : res_e;
            rn = rprev[tid] + hv_g[tid];
        }
        if (bid == 0 && L < DEPTH-1) {          // persist res for next layer
            float* rcur = (L&1) ? res_o : res_e;
            rcur[tid] = rn;
        }
        float ss = rn*rn;
        #pragma unroll
        for (int o = 32; o > 0; o >>= 1) ss += __shfl_down(ss, o, 64);
        if ((tid & 63) == 0) red[tid >> 6] = ss;
        __syncthreads();
        if (tid == 0)
            rstd_s = rsqrtf((red[0]+red[1]+red[2]+red[3]) * (1.f/DD) + 1e-5f);
        __syncthreads();
        hn[tid] = rn * rstd_s * norm_w[L*DD + tid];
        __syncthreads();

        // ---- in_proj slice: 32 cols per block ----
        {
            const float4* W4 = (const float4*)in_proj_w + (size_t)L*DD*128;
            const int seg = tid >> 3;            // 0..31 : d-range of 8
            const int jg  = tid & 7;             // 0..7  : local float4 col
            const int col4 = bid*8 + jg;
            float4 acc = make_float4(0.f,0.f,0.f,0.f);
            #pragma unroll
            for (int i = 0; i < 8; ++i) {
                const int d = seg*8 + i;
                const float h = hn[d];
                const float4 w = W4[(size_t)d*128 + col4];
                acc.x += h*w.x; acc.y += h*w.y; acc.z += h*w.z; acc.w += h*w.w;
            }
            part[seg][jg] = acc;
        }
        __syncthreads();
        if (tid < 32) {
            float s = 0.f;
            #pragma unroll
            for (int g = 0; g < 32; ++g) {
                const float* pp = (const float*)&part[g][tid >> 2];
                s += pp[tid & 3];
            }
            const int gc = bid*32 + tid;
            if (gc < DD) {
                const float pre = conv_w[(L*DD+gc)*4 + 3]*s + conv_b[L*DD+gc];
                xc_g[gc] = pre / (1.f + __expf(-pre));   // silu
            } else {
                zv_g[gc - DD] = s;
            }
        }
        __threadfence();
        grid.sync();
        __threadfence();

        // ---- Stage B: narrow path (redundant) + out_proj slice ----
        xcl[tid] = xc_g[tid];
        zvl[tid] = zv_g[tid];
        __syncthreads();
        if (tid < 192) {                         // x_proj: 48 cols x 4 d-segments
            const int j = tid >> 2, q = tid & 3;
            const float* Wx = x_proj_w + (size_t)L*DD*48;
            float acc = 0.f;
            #pragma unroll 8
            for (int i = 0; i < 64; ++i) {
                const int d = q*64 + i;
                acc += xcl[d] * Wx[(size_t)d*48 + j];
            }
            xp[j][q] = acc;
        }
        __syncthreads();
        if (tid < 48) xdbl[tid] = xp[tid][0] + xp[tid][1] + xp[tid][2] + xp[tid][3];
        __syncthreads();
        {
            const float* Wdt = dt_proj_w + (size_t)L*16*DD;
            float acc = dt_proj_b[L*DD + tid];
            #pragma unroll
            for (int r = 0; r < 16; ++r) acc += xdbl[r] * Wdt[r*DD + tid];
            const float dt = fmaxf(acc, 0.f) + log1pf(__expf(-fabsf(acc)));
            float sbc = 0.f;
            #pragma unroll
            for (int n = 0; n < 16; ++n) sbc += xdbl[16+n] * xdbl[32+n];
            const float y = (dt*sbc + D_skip[L*DD + tid]) * xcl[tid];
            const float z = zvl[tid];
            yvl[tid] = y * (z / (1.f + __expf(-z)));
        }
        __syncthreads();
        {
            const float4* Wo = (const float4*)out_proj_w + (size_t)L*DD*64;
            const int seg = tid >> 2;            // 0..63 : d-range of 4
            const int jg  = tid & 3;             // 0..3  : local float4 col
            const int col4 = bid*4 + jg;
            float4 acc = make_float4(0.f,0.f,0.f,0.f);
            #pragma unroll
            for (int i = 0; i < 4; ++i) {
                const int d = seg*4 + i;
                const float y = yvl[d];
                const float4 w = Wo[(size_t)d*64 + col4];
                acc.x += y*w.x; acc.y += y*w.y; acc.z += y*w.z; acc.w += y*w.w;
            }
            part2[seg][jg] = acc;
        }
        __syncthreads();
        if (tid < 16) {
            float s = 0.f;
            #pragma unroll
            for (int g = 0; g < 64; ++g) {
                const float* pp = (const float*)&part2[g][tid >> 2];
                s += pp[tid & 3];
            }
            hv_g[bid*16 + tid] = s;
        }
        __threadfence();
        grid.sync();
        __threadfence();
    }

    // ---- final rmsnorm (redundant) + broadcast write of 16 rows/block ----
    {
        const float x = hv_g[tid];
        float ss = x*x;
        #pragma unroll
        for (int o = 32; o > 0; o >>= 1) ss += __shfl_down(ss, o, 64);
        if ((tid & 63) == 0) red[tid >> 6] = ss;
        __syncthreads();
        if (tid == 0)
            rstd_s = rsqrtf((red[0]+red[1]+red[2]+red[3]) * (1.f/DD) + 1e-5f);
        __syncthreads();
        hn[tid] = x * rstd_s * norm_f_w[tid];
    }
    __syncthreads();
    {
        const float4* o4 = (const float4*)hn;
        float4* out4 = (float4*)out;
        #pragma unroll
        for (int k = 0; k < 4; ++k) {
            const int idx = k*NTHR + tid;              // 0..1023
            const int row = bid*16 + (idx >> 6);
            out4[(size_t)row*64 + (idx & 63)] = o4[idx & 63];
        }
    }
}

extern "C" void kernel_launch(void* const* d_in, const int* in_sizes, int n_in,
                              void* d_out, int out_size, void* d_ws, size_t ws_size,
                              hipStream_t stream) {
    // 0 x, 1 proj_w, 2 proj_b, 3 cls_token, 4 pos_embed, 5 norm_w, 6 in_proj_w,
    // 7 conv_w, 8 conv_b, 9 x_proj_w, 10 dt_proj_w, 11 dt_proj_b, 12 A_log,
    // 13 D_skip, 14 out_proj_w, 15 norm_f_w
    const float* cls_token = (const float*)d_in[3];
    const float* pos_embed = (const float*)d_in[4];
    const float* norm_w    = (const float*)d_in[5];
    const float* in_proj_w = (const float*)d_in[6];
    const float* conv_w    = (const float*)d_in[7];
    const float* conv_b    = (const float*)d_in[8];
    const float* x_proj_w  = (const float*)d_in[9];
    const float* dt_proj_w = (const float*)d_in[10];
    const float* dt_proj_b = (const float*)d_in[11];
    const float* D_skip    = (const float*)d_in[13];
    const float* out_proj_w= (const float*)d_in[14];
    const float* norm_f_w  = (const float*)d_in[15];
    float* out = (float*)d_out;
    float* ws  = (float*)d_ws;

    void* args[] = { &cls_token, &pos_embed, &norm_w, &in_proj_w, &conv_w, &conv_b,
                     &x_proj_w, &dt_proj_w, &dt_proj_b, &D_skip, &out_proj_w,
                     &norm_f_w, &out, &ws };
    hipLaunchCooperativeKernel((void*)netmamba_coop, dim3(NBLK), dim3(NTHR),
                               args, 0, stream);
}

// Round 3
// 38.118 us; speedup vs baseline: 2.4119x; 2.4119x over previous
//
#include <hip/hip_runtime.h>
#include <math.h>

#define DD 256
#define DEPTH 4
#define XD 48

// cls-position-only network (round-1 derivation, absmax 0.0).
// Round 3: stage kernels in-stream; kernel boundaries are the grid barriers
// (HW dispatch, no coop grid.sync, no explicit fences -> no L2 thrash).
// ws layout: [0,256) xc | [256,512) zv | [512,768) hv | [768,1024) res_even |
//            [1024,1280) res_odd

// ---- stage A: residual + rmsnorm + in_proj slice + conv@t0 + silu ----
// grid 32 x 256 threads; block owns 16 of 512 output cols.
__global__ __launch_bounds__(256, 1)
void stageA(int L,
            const float* __restrict__ cls_token,
            const float* __restrict__ pos_embed,
            const float* __restrict__ norm_w,
            const float* __restrict__ in_proj_w,
            const float* __restrict__ conv_w,
            const float* __restrict__ conv_b,
            float* __restrict__ ws)
{
    const int tid = threadIdx.x, bid = blockIdx.x;
    float* xc_g = ws;
    float* zv_g = ws + DD;
    const float* hv_g = ws + 2*DD;
    float* res_e = ws + 3*DD;
    float* res_o = ws + 4*DD;

    __shared__ float hn[DD];
    __shared__ float4 part[64][4];
    __shared__ float red[4];
    __shared__ float rstd_s;

    // residual (redundant per block; block 0 persists it, parity-buffered)
    float rn;
    if (L == 0) rn = cls_token[tid] + pos_embed[50*DD + tid];
    else        rn = ((L-1) & 1 ? res_o : res_e)[tid] + hv_g[tid];
    if (bid == 0) ((L & 1) ? res_o : res_e)[tid] = rn;

    float ss = rn * rn;
    #pragma unroll
    for (int o = 32; o > 0; o >>= 1) ss += __shfl_down(ss, o, 64);
    if ((tid & 63) == 0) red[tid >> 6] = ss;
    __syncthreads();
    if (tid == 0)
        rstd_s = rsqrtf((red[0]+red[1]+red[2]+red[3]) * (1.f/DD) + 1e-5f);
    __syncthreads();
    hn[tid] = rn * rstd_s * norm_w[L*DD + tid];
    __syncthreads();

    // in_proj slice: cols [bid*16, bid*16+16) of 512
    {
        const float4* W4 = (const float4*)in_proj_w + (size_t)L * DD * 128;
        const int c = tid & 3, seg = tid >> 2;       // 64 segs x 4 rows
        const int col4 = bid*4 + c;
        float4 acc = make_float4(0.f, 0.f, 0.f, 0.f);
        #pragma unroll
        for (int i = 0; i < 4; ++i) {
            const int d = seg*4 + i;
            const float h = hn[d];
            const float4 w = W4[(size_t)d*128 + col4];
            acc.x += h*w.x; acc.y += h*w.y; acc.z += h*w.z; acc.w += h*w.w;
        }
        part[seg][c] = acc;
    }
    __syncthreads();
    #pragma unroll
    for (int off = 32; off >= 8; off >>= 1) {
        const int s = tid >> 2, c = tid & 3;
        if (s < off) {
            float4 a = part[s][c], b = part[s+off][c];
            a.x += b.x; a.y += b.y; a.z += b.z; a.w += b.w;
            part[s][c] = a;
        }
        __syncthreads();
    }
    if (tid < 16) {
        const int j = tid;
        float s = 0.f;
        #pragma unroll
        for (int g = 0; g < 8; ++g)
            s += ((const float*)&part[g][j >> 2])[j & 3];
        const int gc = bid*16 + j;
        if (gc < DD) {
            const float pre = conv_w[(L*DD + gc)*4 + 3]*s + conv_b[L*DD + gc];
            xc_g[gc] = pre / (1.f + __expf(-pre));       // silu
        } else {
            zv_g[gc - DD] = s;
        }
    }
}

// ---- stage B: x_proj + dt + scan(t=0) + gate (redundant) + out_proj slice ----
// grid 16 x 256 threads; block owns 16 of 256 output cols.
__global__ __launch_bounds__(256, 1)
void stageB(int L,
            const float* __restrict__ x_proj_w,
            const float* __restrict__ dt_proj_w,
            const float* __restrict__ dt_proj_b,
            const float* __restrict__ D_skip,
            const float* __restrict__ out_proj_w,
            float* __restrict__ ws)
{
    const int tid = threadIdx.x, bid = blockIdx.x;
    const float* xc_g = ws;
    const float* zv_g = ws + DD;
    float* hv_g = ws + 2*DD;

    __shared__ float xcl[DD], yv[DD], xdbl[XD];
    __shared__ float xp[XD][4];
    __shared__ float4 part[64][4];

    xcl[tid] = xc_g[tid];
    const float zval = zv_g[tid];
    __syncthreads();

    if (tid < 192) {                      // x_proj: 48 cols x 4 d-segments
        const int j = tid >> 2, q = tid & 3;
        const float* Wx = x_proj_w + (size_t)L * DD * XD;
        float acc = 0.f;
        #pragma unroll 8
        for (int i = 0; i < 64; ++i) {
            const int d = q*64 + i;
            acc += xcl[d] * Wx[(size_t)d*XD + j];
        }
        xp[j][q] = acc;
    }
    __syncthreads();
    if (tid < XD) xdbl[tid] = xp[tid][0] + xp[tid][1] + xp[tid][2] + xp[tid][3];
    __syncthreads();

    {
        const float* Wdt = dt_proj_w + (size_t)L * 16 * DD;
        float acc = dt_proj_b[L*DD + tid];
        #pragma unroll
        for (int r = 0; r < 16; ++r) acc += xdbl[r] * Wdt[r*DD + tid];
        const float dt = fmaxf(acc, 0.f) + log1pf(__expf(-fabsf(acc)));  // softplus
        float sbc = 0.f;
        #pragma unroll
        for (int n = 0; n < 16; ++n) sbc += xdbl[16+n] * xdbl[32+n];     // B.C
        const float y = (dt*sbc + D_skip[L*DD + tid]) * xcl[tid];
        yv[tid] = y * (zval / (1.f + __expf(-zval)));                    // * silu(z)
    }
    __syncthreads();

    // out_proj slice: cols [bid*16, bid*16+16) of 256
    {
        const float4* Wo = (const float4*)out_proj_w + (size_t)L * DD * 64;
        const int c = tid & 3, seg = tid >> 2;
        const int col4 = bid*4 + c;
        float4 acc = make_float4(0.f, 0.f, 0.f, 0.f);
        #pragma unroll
        for (int i = 0; i < 4; ++i) {
            const int d = seg*4 + i;
            const float y = yv[d];
            const float4 w = Wo[(size_t)d*64 + col4];
            acc.x += y*w.x; acc.y += y*w.y; acc.z += y*w.z; acc.w += y*w.w;
        }
        part[seg][c] = acc;
    }
    __syncthreads();
    #pragma unroll
    for (int off = 32; off >= 8; off >>= 1) {
        const int s = tid >> 2, c = tid & 3;
        if (s < off) {
            float4 a = part[s][c], b = part[s+off][c];
            a.x += b.x; a.y += b.y; a.z += b.z; a.w += b.w;
            part[s][c] = a;
        }
        __syncthreads();
    }
    if (tid < 16) {
        const int j = tid;
        float s = 0.f;
        #pragma unroll
        for (int g = 0; g < 8; ++g)
            s += ((const float*)&part[g][j >> 2])[j & 3];
        hv_g[bid*16 + j] = s;
    }
}

// ---- final: rmsnorm(hv) (redundant) + broadcast 16 rows per block ----
__global__ __launch_bounds__(256, 1)
void finalK(const float* __restrict__ norm_f_w,
            const float* __restrict__ ws,
            float* __restrict__ out)
{
    const int tid = threadIdx.x, bid = blockIdx.x;
    const float* hv_g = ws + 2*DD;
    __shared__ float hn[DD];
    __shared__ float red[4];
    __shared__ float rstd_s;

    const float x = hv_g[tid];
    float ss = x * x;
    #pragma unroll
    for (int o = 32; o > 0; o >>= 1) ss += __shfl_down(ss, o, 64);
    if ((tid & 63) == 0) red[tid >> 6] = ss;
    __syncthreads();
    if (tid == 0)
        rstd_s = rsqrtf((red[0]+red[1]+red[2]+red[3]) * (1.f/DD) + 1e-5f);
    __syncthreads();
    hn[tid] = x * rstd_s * norm_f_w[tid];
    __syncthreads();

    const float4* o4 = (const float4*)hn;
    float4* out4 = (float4*)out;
    #pragma unroll
    for (int k = 0; k < 4; ++k) {
        const int idx = k*256 + tid;               // 0..1023
        const int row = bid*16 + (idx >> 6);
        out4[(size_t)row*64 + (idx & 63)] = o4[idx & 63];
    }
}

extern "C" void kernel_launch(void* const* d_in, const int* in_sizes, int n_in,
                              void* d_out, int out_size, void* d_ws, size_t ws_size,
                              hipStream_t stream) {
    // 0 x, 1 proj_w, 2 proj_b, 3 cls_token, 4 pos_embed, 5 norm_w, 6 in_proj_w,
    // 7 conv_w, 8 conv_b, 9 x_proj_w, 10 dt_proj_w, 11 dt_proj_b, 12 A_log,
    // 13 D_skip, 14 out_proj_w, 15 norm_f_w
    const float* cls_token  = (const float*)d_in[3];
    const float* pos_embed  = (const float*)d_in[4];
    const float* norm_w     = (const float*)d_in[5];
    const float* in_proj_w  = (const float*)d_in[6];
    const float* conv_w     = (const float*)d_in[7];
    const float* conv_b     = (const float*)d_in[8];
    const float* x_proj_w   = (const float*)d_in[9];
    const float* dt_proj_w  = (const float*)d_in[10];
    const float* dt_proj_b  = (const float*)d_in[11];
    const float* D_skip     = (const float*)d_in[13];
    const float* out_proj_w = (const float*)d_in[14];
    const float* norm_f_w   = (const float*)d_in[15];
    float* out = (float*)d_out;
    float* ws  = (float*)d_ws;

    for (int L = 0; L < DEPTH; ++L) {
        stageA<<<dim3(32), dim3(256), 0, stream>>>(
            L, cls_token, pos_embed, norm_w, in_proj_w, conv_w, conv_b, ws);
        stageB<<<dim3(16), dim3(256), 0, stream>>>(
            L, x_proj_w, dt_proj_w, dt_proj_b, D_skip, out_proj_w, ws);
    }
    finalK<<<dim3(16), dim3(256), 0, stream>>>(norm_f_w, ws, out);
}